// Round 3
// baseline (281.515 us; speedup 1.0000x reference)
//
#include <hip/hip_runtime.h>
#include <float.h>

#define NB 64  // n_bins (bins array has NB+1 edges)

typedef float vfloat4 __attribute__((ext_vector_type(4)));

// R3: MEASUREMENT PROBE — kernel body is bit-identical to R0 (best, 245.66us).
// kernel_launch enqueues it TWICE back-to-back. Output is idempotent, so
// correctness/absmax are unchanged. Purpose: dur_us(R3) - dur_us(R0) = the
// steady-state cost of ONE kernel dispatch, which rocprof's top-5 window
// hides (all 5 slots are ~154us harness poison fills; our kernel is <152us).
// This discriminates: kernel ~45us (near write-roofline of 260MB @ 6.5TB/s,
// remaining time is untouchable harness fills) vs kernel ~90us (a real
// structure-invariant ~2.9TB/s store wall worth attacking).
__global__ __launch_bounds__(256) void ple_kernel(const float* __restrict__ x,
                                                  const float* __restrict__ bins,
                                                  float* __restrict__ out,
                                                  long long total4) {
    __shared__ __align__(16) float s_rinv[NB];
    __shared__ __align__(16) float s_nlor[NB];
    __shared__ __align__(16) float s_cl[NB];
    __shared__ __align__(16) float s_ch[NB];

    const int tid = threadIdx.x;
    if (tid < NB) {
        const float lo   = bins[tid];
        const float hi   = bins[tid + 1];
        const float rinv = 1.0f / (hi - lo);   // off the hot path: once per block
        s_rinv[tid] = rinv;
        s_nlor[tid] = -lo * rinv;
        s_cl[tid] = (tid == 0)      ? -FLT_MAX : 0.0f;   // bin 0: no left clamp
        s_ch[tid] = (tid == NB - 1) ?  FLT_MAX : 1.0f;   // bin 63: no right clamp
    }
    __syncthreads();

    const int j4 = (tid & 15) << 2;            // this thread's 4 bins (loop-invariant)
    const vfloat4 rinv4 = *(const vfloat4*)&s_rinv[j4];
    const vfloat4 nlor4 = *(const vfloat4*)&s_nlor[j4];
    const vfloat4 cl4   = *(const vfloat4*)&s_cl[j4];
    const vfloat4 ch4   = *(const vfloat4*)&s_ch[j4];

    const long long base = (long long)blockIdx.x * 1024 + tid;

    long long t[4];
    float xv[4];
#pragma unroll
    for (int k = 0; k < 4; ++k) {              // 4 independent loads, issued together
        t[k] = base + (long long)(k << 8);
        xv[k] = (t[k] < total4) ? x[t[k] >> 4] : 0.0f;
    }

#pragma unroll
    for (int k = 0; k < 4; ++k) {
        vfloat4 r;
#pragma unroll
        for (int c = 0; c < 4; ++c) {
            const float v = fmaf(xv[k], rinv4[c], nlor4[c]);
            r[c] = fminf(fmaxf(v, cl4[c]), ch4[c]);
        }
        if (t[k] < total4)
            *((vfloat4*)out + t[k]) = r;       // plain store (write-back L2 path)
    }
}

extern "C" void kernel_launch(void* const* d_in, const int* in_sizes, int n_in,
                              void* d_out, int out_size, void* d_ws, size_t ws_size,
                              hipStream_t stream) {
    const float* x    = (const float*)d_in[0];
    const float* bins = (const float*)d_in[1];
    float* out        = (float*)d_out;

    const int batch = in_sizes[0];                   // x is (BATCH, 1)
    const long long total4 = (long long)batch * (NB / 4);
    const long long grid = (total4 + 1023) / 1024;   // 15625 for BATCH=1e6 (exact)

    // Launch TWICE: second dispatch is an exact idempotent replica; the
    // dur_us delta vs the single-launch baseline measures one warm dispatch.
    ple_kernel<<<(dim3)(unsigned)grid, 256, 0, stream>>>(x, bins, out, total4);
    ple_kernel<<<(dim3)(unsigned)grid, 256, 0, stream>>>(x, bins, out, total4);
}

// Round 4
// 246.829 us; speedup vs baseline: 1.1405x; 1.1405x over previous
//
#include <hip/hip_runtime.h>
#include <float.h>

#define NB 64  // n_bins (bins array has NB+1 edges)

typedef float vfloat4 __attribute__((ext_vector_type(4)));

// R4: restored R0 (best, 245.66us) after the R3 double-launch probe measured
// one warm kernel dispatch at 35.9us vs a 39.4us memory roofline (260MB
// traffic @ 6.6TB/s achievable; out=256MB ~ L3 capacity, so warm stores
// partially retire in Infinity Cache). The kernel is AT the write roofline.
// The remaining ~210us of dur_us is harness poison (a 1.024GB fill is
// directly visible in rocprof at ~154us) — untouchable from kernel_launch.
// Structure-invariance confirms it: short blocks (R0), persistent grid-stride
// (R1), sequential 256KB spans (R2) all within 2%.
//
// Each block covers 1024 consecutive float4-slots (256 threads x 4 slots at
// +256 stride). 4 independent x loads per thread issue together -> 4x MLP.
// Stores are PLAIN (write-back via L2): nt-flagged stores measured ~3.1 TB/s
// in a prior session vs 6.3 TB/s plain.
__global__ __launch_bounds__(256) void ple_kernel(const float* __restrict__ x,
                                                  const float* __restrict__ bins,
                                                  float* __restrict__ out,
                                                  long long total4) {
    __shared__ __align__(16) float s_rinv[NB];
    __shared__ __align__(16) float s_nlor[NB];
    __shared__ __align__(16) float s_cl[NB];
    __shared__ __align__(16) float s_ch[NB];

    const int tid = threadIdx.x;
    if (tid < NB) {
        const float lo   = bins[tid];
        const float hi   = bins[tid + 1];
        const float rinv = 1.0f / (hi - lo);   // off the hot path: once per block
        s_rinv[tid] = rinv;
        s_nlor[tid] = -lo * rinv;
        s_cl[tid] = (tid == 0)      ? -FLT_MAX : 0.0f;   // bin 0: no left clamp
        s_ch[tid] = (tid == NB - 1) ?  FLT_MAX : 1.0f;   // bin 63: no right clamp
    }
    __syncthreads();

    const int j4 = (tid & 15) << 2;            // this thread's 4 bins (loop-invariant)
    const vfloat4 rinv4 = *(const vfloat4*)&s_rinv[j4];
    const vfloat4 nlor4 = *(const vfloat4*)&s_nlor[j4];
    const vfloat4 cl4   = *(const vfloat4*)&s_cl[j4];
    const vfloat4 ch4   = *(const vfloat4*)&s_ch[j4];

    const long long base = (long long)blockIdx.x * 1024 + tid;

    long long t[4];
    float xv[4];
#pragma unroll
    for (int k = 0; k < 4; ++k) {              // 4 independent loads, issued together
        t[k] = base + (long long)(k << 8);
        xv[k] = (t[k] < total4) ? x[t[k] >> 4] : 0.0f;
    }

#pragma unroll
    for (int k = 0; k < 4; ++k) {
        vfloat4 r;
#pragma unroll
        for (int c = 0; c < 4; ++c) {
            const float v = fmaf(xv[k], rinv4[c], nlor4[c]);
            r[c] = fminf(fmaxf(v, cl4[c]), ch4[c]);
        }
        if (t[k] < total4)
            *((vfloat4*)out + t[k]) = r;       // plain store (write-back L2 path)
    }
}

extern "C" void kernel_launch(void* const* d_in, const int* in_sizes, int n_in,
                              void* d_out, int out_size, void* d_ws, size_t ws_size,
                              hipStream_t stream) {
    const float* x    = (const float*)d_in[0];
    const float* bins = (const float*)d_in[1];
    float* out        = (float*)d_out;

    const int batch = in_sizes[0];                   // x is (BATCH, 1)
    const long long total4 = (long long)batch * (NB / 4);
    const long long grid = (total4 + 1023) / 1024;   // 15625 for BATCH=1e6 (exact)

    ple_kernel<<<(dim3)(unsigned)grid, 256, 0, stream>>>(x, bins, out, total4);
}